// Round 8
// baseline (234.046 us; speedup 1.0000x reference)
//
#include <hip/hip_runtime.h>
#include <stdint.h>

#define BB 2
#define HH 16
#define TT 2048
#define DD 64
#define NHASH 4
#define NHALF 32   // num_buckets/2

// ---------------- Phase 1: compute packed bucket words ----------------
// (exact round-6 kernel — 134.2 us total with single mask launch)
__global__ __launch_bounds__(256, 3) void lsh_buckets_kernel(
    const float* __restrict__ hs,    // [BB, TT, HH*DD]
    const float* __restrict__ rot,   // [HH, DD, NHASH, NHALF]
    uint32_t* __restrict__ words)    // [BB*HH*TT]
{
    __shared__ uint32_t lds[12288];            // 48 KiB
    float4* v4 = (float4*)lds;                 // [64 t][16 slots]   (16 KiB)
    float4* r4 = (float4*)(lds + 4096);        // [4 n][32 r][16 slots] (32 KiB)

    const int blk  = blockIdx.x;
    const int bh   = blk >> 5;        // / (TT/64)
    const int tblk = blk & 31;
    const int b    = bh >> 4;
    const int h    = bh & 15;
    const int t0   = tblk * 64;
    const int tid  = threadIdx.x;
    const int n    = tid >> 6;        // wave = hash
    const int lane = tid & 63;
    const int tg   = lane >> 3;       // token group (8 tokens)
    const int rg   = lane & 7;        // r group (4 r's)

    // ---- stage v tile: [64 t][64 d] f32, slot = d4 ^ (t>>3) ----
    #pragma unroll
    for (int p = 0; p < 4; ++p) {
        const int k  = tid + p * 256;       // 0..1023 float4s
        const int t  = k >> 4;
        const int d4 = k & 15;
        const float4 f = ((const float4*)(hs + ((size_t)(b * TT + t0 + t)) * (HH * DD) + h * DD))[d4];
        v4[t * 16 + (d4 ^ (t >> 3))] = f;
    }
    // ---- stage rot: [4 n][32 r][64 d] f32, slot = d4 ^ (r>>2) ----
    {
        const float* rh = rot + (size_t)h * (DD * NHASH * NHALF);
        float* rf = (float*)r4;
        #pragma unroll
        for (int p = 0; p < 32; ++p) {
            const int g  = tid + p * 256;   // global idx: d*128 + n*32 + r (coalesced)
            const int d  = g >> 7;
            const int nr = g & 127;
            const int nn = nr >> 5;
            const int r  = nr & 31;
            const int slot = (d >> 2) ^ (r >> 2);
            rf[((nn * 32 + r) * 16 + slot) * 4 + (d & 3)] = rh[g];
        }
    }
    __syncthreads();

    // ---- K loop: acc[i][j] (t = tg*8+i, r = rg*4+j), f64 ----
    double acc[8][4];
    #pragma unroll
    for (int i = 0; i < 8; ++i)
        #pragma unroll
        for (int j = 0; j < 4; ++j) acc[i][j] = 0.0;

    const int vbase = tg * 8 * 16;                 // float4 index of first own token row
    const int rbase = (n * 32 + rg * 4) * 16;      // float4 index of first own r row

    for (int s = 0; s < 16; ++s) {                 // d = s*4 .. s*4+3
        double rd[4][4];
        #pragma unroll
        for (int j = 0; j < 4; ++j) {
            const float4 rf = r4[rbase + j * 16 + (s ^ rg)];
            rd[j][0] = (double)rf.x; rd[j][1] = (double)rf.y;
            rd[j][2] = (double)rf.z; rd[j][3] = (double)rf.w;
        }
        #pragma unroll
        for (int i = 0; i < 8; ++i) {
            const float4 vf = v4[vbase + i * 16 + (s ^ tg)];
            const double v0 = (double)vf.x, v1 = (double)vf.y;
            const double v2 = (double)vf.z, v3 = (double)vf.w;
            #pragma unroll
            for (int j = 0; j < 4; ++j) {
                acc[i][j] += v0 * rd[j][0];
                acc[i][j] += v1 * rd[j][1];
                acc[i][j] += v2 * rd[j][2];
                acc[i][j] += v3 * rd[j][3];
            }
        }
    }

    // ---- epilogue: argmax/argmin over r per (n,t) ----
    __syncthreads();   // all LDS reads done; alias lds for partials
    float*    vmaxL = (float*)lds;            // [4][64][9]
    float*    vminL = (float*)(lds + 2304);
    uint32_t* imaxL = lds + 4608;
    uint32_t* iminL = lds + 6912;
    uint32_t* bkt   = lds + 9216;             // [4][64]

    #pragma unroll
    for (int i = 0; i < 8; ++i) {
        const int t = tg * 8 + i;
        float fmx = -INFINITY; int imx = 0;
        float fmn =  INFINITY; int imn = 0;
        #pragma unroll
        for (int j = 0; j < 4; ++j) {
            const float f = (float)acc[i][j];
            const int   r = rg * 4 + j;
            if (f > fmx) { fmx = f; imx = r; }
            if (f < fmn) { fmn = f; imn = r; }
        }
        const int o = (n * 64 + t) * 9 + rg;
        vmaxL[o] = fmx; vminL[o] = fmn;
        imaxL[o] = (uint32_t)imx; iminL[o] = (uint32_t)imn;
    }
    __syncthreads();
    {
        const int nn = tid >> 6;
        const int t  = tid & 63;
        float fmx = -INFINITY; int imx = 0;
        float fmn =  INFINITY; int imn = 0;
        #pragma unroll
        for (int g = 0; g < 8; ++g) {     // rg ascending -> r ascending: first-index tie-break
            const int o = (nn * 64 + t) * 9 + g;
            const float fx = vmaxL[o];
            const float fn = vminL[o];
            if (fx > fmx) { fmx = fx; imx = (int)imaxL[o]; }
            if (fn < fmn) { fmn = fn; imn = (int)iminL[o]; }
        }
        const uint32_t bucket = (fmx >= -fmn) ? (uint32_t)imx : (uint32_t)(NHALF + imn);
        bkt[nn * 64 + t] = bucket;
    }
    __syncthreads();
    if (tid < 64) {
        words[(size_t)bh * TT + t0 + tid] = bkt[tid]
                                          | (bkt[64  + tid] << 8)
                                          | (bkt[128 + tid] << 16)
                                          | (bkt[192 + tid] << 24);
    }
}

// ---------------- Phase 2: materialize the [B,H,T,T] mask (int32 0/1) ----------------
#define ROWS 8
__device__ __forceinline__ uint32_t eq_any_byte(uint32_t a, uint32_t b) {
    const uint32_t x = a ^ b;
    return ((x - 0x01010101u) & ~x & 0x80808080u) ? 1u : 0u;
}

__global__ __launch_bounds__(256) void lsh_mask_kernel(
    const uint32_t* __restrict__ words,  // [BB*HH*TT]
    uint4* __restrict__ out)             // [BB*HH*TT][TT/4]
{
    const int bh  = blockIdx.x >> 8;            // TT/ROWS = 256 blocks per bh
    const int i0  = (blockIdx.x & 255) * ROWS;
    const int tid = threadIdx.x;
    const uint32_t* wrow = words + (bh << 11);

    const uint4 wj0 = ((const uint4*)wrow)[tid];        // j = tid*4
    const uint4 wj1 = ((const uint4*)wrow)[tid + 256];  // j = tid*4 + 1024

    #pragma unroll
    for (int k = 0; k < ROWS; ++k) {
        const uint32_t wi = wrow[i0 + k];
        uint4 r0, r1;
        r0.x = eq_any_byte(wi, wj0.x); r0.y = eq_any_byte(wi, wj0.y);
        r0.z = eq_any_byte(wi, wj0.z); r0.w = eq_any_byte(wi, wj0.w);
        r1.x = eq_any_byte(wi, wj1.x); r1.y = eq_any_byte(wi, wj1.y);
        r1.z = eq_any_byte(wi, wj1.z); r1.w = eq_any_byte(wi, wj1.w);
        uint4* op = out + (((size_t)((bh << 11) + i0 + k)) << 9);
        op[tid]       = r0;
        op[tid + 256] = r1;
    }
}

extern "C" void kernel_launch(void* const* d_in, const int* in_sizes, int n_in,
                              void* d_out, int out_size, void* d_ws, size_t ws_size,
                              hipStream_t stream) {
    const float* hs  = (const float*)d_in[0];   // [2, 2048, 1024] f32
    const float* rot = (const float*)d_in[1];   // [16, 64, 4, 32] f32
    uint32_t* words  = (uint32_t*)d_ws;         // needs BB*HH*TT*4 = 512 KiB

    lsh_buckets_kernel<<<BB * HH * (TT / 64), 256, 0, stream>>>(hs, rot, words);
    // DIAGNOSTIC: launch the (idempotent) mask kernel TWICE.
    // dur_us - 134.2 (round-6 single-launch baseline) = P2 exactly.
    lsh_mask_kernel<<<BB * HH * (TT / ROWS), 256, 0, stream>>>(words, (uint4*)d_out);
    lsh_mask_kernel<<<BB * HH * (TT / ROWS), 256, 0, stream>>>(words, (uint4*)d_out);
}

// Round 9
// 142.683 us; speedup vs baseline: 1.6403x; 1.6403x over previous
//
#include <hip/hip_runtime.h>
#include <stdint.h>

#define BB 2
#define HH 16
#define TT 2048
#define DD 64
#define NHASH 4
#define NHALF 32   // num_buckets/2

typedef uint32_t u32x4 __attribute__((ext_vector_type(4)));

// ---------------- Phase 1: compute packed bucket words ----------------
// (exact round-6 kernel — best known; P1 ~= 34 us incl. launch overhead)
__global__ __launch_bounds__(256, 3) void lsh_buckets_kernel(
    const float* __restrict__ hs,    // [BB, TT, HH*DD]
    const float* __restrict__ rot,   // [HH, DD, NHASH, NHALF]
    uint32_t* __restrict__ words)    // [BB*HH*TT]
{
    __shared__ uint32_t lds[12288];            // 48 KiB
    float4* v4 = (float4*)lds;                 // [64 t][16 slots]   (16 KiB)
    float4* r4 = (float4*)(lds + 4096);        // [4 n][32 r][16 slots] (32 KiB)

    const int blk  = blockIdx.x;
    const int bh   = blk >> 5;        // / (TT/64)
    const int tblk = blk & 31;
    const int b    = bh >> 4;
    const int h    = bh & 15;
    const int t0   = tblk * 64;
    const int tid  = threadIdx.x;
    const int n    = tid >> 6;        // wave = hash
    const int lane = tid & 63;
    const int tg   = lane >> 3;       // token group (8 tokens)
    const int rg   = lane & 7;        // r group (4 r's)

    // ---- stage v tile: [64 t][64 d] f32, slot = d4 ^ (t>>3) ----
    #pragma unroll
    for (int p = 0; p < 4; ++p) {
        const int k  = tid + p * 256;       // 0..1023 float4s
        const int t  = k >> 4;
        const int d4 = k & 15;
        const float4 f = ((const float4*)(hs + ((size_t)(b * TT + t0 + t)) * (HH * DD) + h * DD))[d4];
        v4[t * 16 + (d4 ^ (t >> 3))] = f;
    }
    // ---- stage rot: [4 n][32 r][64 d] f32, slot = d4 ^ (r>>2) ----
    {
        const float* rh = rot + (size_t)h * (DD * NHASH * NHALF);
        float* rf = (float*)r4;
        #pragma unroll
        for (int p = 0; p < 32; ++p) {
            const int g  = tid + p * 256;   // global idx: d*128 + n*32 + r (coalesced)
            const int d  = g >> 7;
            const int nr = g & 127;
            const int nn = nr >> 5;
            const int r  = nr & 31;
            const int slot = (d >> 2) ^ (r >> 2);
            rf[((nn * 32 + r) * 16 + slot) * 4 + (d & 3)] = rh[g];
        }
    }
    __syncthreads();

    // ---- K loop: acc[i][j] (t = tg*8+i, r = rg*4+j), f64 ----
    double acc[8][4];
    #pragma unroll
    for (int i = 0; i < 8; ++i)
        #pragma unroll
        for (int j = 0; j < 4; ++j) acc[i][j] = 0.0;

    const int vbase = tg * 8 * 16;                 // float4 index of first own token row
    const int rbase = (n * 32 + rg * 4) * 16;      // float4 index of first own r row

    for (int s = 0; s < 16; ++s) {                 // d = s*4 .. s*4+3
        double rd[4][4];
        #pragma unroll
        for (int j = 0; j < 4; ++j) {
            const float4 rf = r4[rbase + j * 16 + (s ^ rg)];
            rd[j][0] = (double)rf.x; rd[j][1] = (double)rf.y;
            rd[j][2] = (double)rf.z; rd[j][3] = (double)rf.w;
        }
        #pragma unroll
        for (int i = 0; i < 8; ++i) {
            const float4 vf = v4[vbase + i * 16 + (s ^ tg)];
            const double v0 = (double)vf.x, v1 = (double)vf.y;
            const double v2 = (double)vf.z, v3 = (double)vf.w;
            #pragma unroll
            for (int j = 0; j < 4; ++j) {
                acc[i][j] += v0 * rd[j][0];
                acc[i][j] += v1 * rd[j][1];
                acc[i][j] += v2 * rd[j][2];
                acc[i][j] += v3 * rd[j][3];
            }
        }
    }

    // ---- epilogue: argmax/argmin over r per (n,t) ----
    __syncthreads();   // all LDS reads done; alias lds for partials
    float*    vmaxL = (float*)lds;            // [4][64][9]
    float*    vminL = (float*)(lds + 2304);
    uint32_t* imaxL = lds + 4608;
    uint32_t* iminL = lds + 6912;
    uint32_t* bkt   = lds + 9216;             // [4][64]

    #pragma unroll
    for (int i = 0; i < 8; ++i) {
        const int t = tg * 8 + i;
        float fmx = -INFINITY; int imx = 0;
        float fmn =  INFINITY; int imn = 0;
        #pragma unroll
        for (int j = 0; j < 4; ++j) {
            const float f = (float)acc[i][j];
            const int   r = rg * 4 + j;
            if (f > fmx) { fmx = f; imx = r; }
            if (f < fmn) { fmn = f; imn = r; }
        }
        const int o = (n * 64 + t) * 9 + rg;
        vmaxL[o] = fmx; vminL[o] = fmn;
        imaxL[o] = (uint32_t)imx; iminL[o] = (uint32_t)imn;
    }
    __syncthreads();
    {
        const int nn = tid >> 6;
        const int t  = tid & 63;
        float fmx = -INFINITY; int imx = 0;
        float fmn =  INFINITY; int imn = 0;
        #pragma unroll
        for (int g = 0; g < 8; ++g) {     // rg ascending -> r ascending: first-index tie-break
            const int o = (nn * 64 + t) * 9 + g;
            const float fx = vmaxL[o];
            const float fn = vminL[o];
            if (fx > fmx) { fmx = fx; imx = (int)imaxL[o]; }
            if (fn < fmn) { fmn = fn; imn = (int)iminL[o]; }
        }
        const uint32_t bucket = (fmx >= -fmn) ? (uint32_t)imx : (uint32_t)(NHALF + imn);
        bkt[nn * 64 + t] = bucket;
    }
    __syncthreads();
    if (tid < 64) {
        words[(size_t)bh * TT + t0 + tid] = bkt[tid]
                                          | (bkt[64  + tid] << 8)
                                          | (bkt[128 + tid] << 16)
                                          | (bkt[192 + tid] << 24);
    }
}

// ---------------- Phase 2: materialize the [B,H,T,T] mask (int32 0/1) ----------------
// ONLY change vs round 6: nontemporal stores (output never re-read; skip
// L2 write-allocate for the 512 MiB stream).
#define ROWS 8
__device__ __forceinline__ uint32_t eq_any_byte(uint32_t a, uint32_t b) {
    const uint32_t x = a ^ b;
    return ((x - 0x01010101u) & ~x & 0x80808080u) ? 1u : 0u;
}

__global__ __launch_bounds__(256) void lsh_mask_kernel(
    const uint32_t* __restrict__ words,  // [BB*HH*TT]
    uint32_t* __restrict__ out)          // [BB*HH*TT][TT]
{
    const int bh  = blockIdx.x >> 8;            // TT/ROWS = 256 blocks per bh
    const int i0  = (blockIdx.x & 255) * ROWS;
    const int tid = threadIdx.x;
    const uint32_t* wrow = words + (bh << 11);

    const uint4 wj0 = ((const uint4*)wrow)[tid];        // j = tid*4
    const uint4 wj1 = ((const uint4*)wrow)[tid + 256];  // j = tid*4 + 1024

    #pragma unroll
    for (int k = 0; k < ROWS; ++k) {
        const uint32_t wi = wrow[i0 + k];
        u32x4 r0, r1;
        r0.x = eq_any_byte(wi, wj0.x); r0.y = eq_any_byte(wi, wj0.y);
        r0.z = eq_any_byte(wi, wj0.z); r0.w = eq_any_byte(wi, wj0.w);
        r1.x = eq_any_byte(wi, wj1.x); r1.y = eq_any_byte(wi, wj1.y);
        r1.z = eq_any_byte(wi, wj1.z); r1.w = eq_any_byte(wi, wj1.w);
        uint32_t* op = out + (((size_t)((bh << 11) + i0 + k)) << 11);
        __builtin_nontemporal_store(r0, (u32x4*)op + tid);
        __builtin_nontemporal_store(r1, (u32x4*)op + tid + 256);
    }
}

extern "C" void kernel_launch(void* const* d_in, const int* in_sizes, int n_in,
                              void* d_out, int out_size, void* d_ws, size_t ws_size,
                              hipStream_t stream) {
    const float* hs  = (const float*)d_in[0];   // [2, 2048, 1024] f32
    const float* rot = (const float*)d_in[1];   // [16, 64, 4, 32] f32
    uint32_t* words  = (uint32_t*)d_ws;         // needs BB*HH*TT*4 = 512 KiB

    lsh_buckets_kernel<<<BB * HH * (TT / 64), 256, 0, stream>>>(hs, rot, words);
    lsh_mask_kernel<<<BB * HH * (TT / ROWS), 256, 0, stream>>>(words, (uint32_t*)d_out);
}

// Round 10
// 126.745 us; speedup vs baseline: 1.8466x; 1.1257x over previous
//
#include <hip/hip_runtime.h>
#include <stdint.h>

#define BB 2
#define HH 16
#define TT 2048
#define DD 64
#define NHASH 4
#define NHALF 32   // num_buckets/2

// ---------------- Phase 1: compute packed bucket words ----------------
// (exact round-6 kernel — best known; P1 ~= 30 us + launch overhead)
__global__ __launch_bounds__(256, 3) void lsh_buckets_kernel(
    const float* __restrict__ hs,    // [BB, TT, HH*DD]
    const float* __restrict__ rot,   // [HH, DD, NHASH, NHALF]
    uint32_t* __restrict__ words)    // [BB*HH*TT]
{
    __shared__ uint32_t lds[12288];            // 48 KiB
    float4* v4 = (float4*)lds;                 // [64 t][16 slots]   (16 KiB)
    float4* r4 = (float4*)(lds + 4096);        // [4 n][32 r][16 slots] (32 KiB)

    const int blk  = blockIdx.x;
    const int bh   = blk >> 5;        // / (TT/64)
    const int tblk = blk & 31;
    const int b    = bh >> 4;
    const int h    = bh & 15;
    const int t0   = tblk * 64;
    const int tid  = threadIdx.x;
    const int n    = tid >> 6;        // wave = hash
    const int lane = tid & 63;
    const int tg   = lane >> 3;       // token group (8 tokens)
    const int rg   = lane & 7;        // r group (4 r's)

    // ---- stage v tile: [64 t][64 d] f32, slot = d4 ^ (t>>3) ----
    #pragma unroll
    for (int p = 0; p < 4; ++p) {
        const int k  = tid + p * 256;       // 0..1023 float4s
        const int t  = k >> 4;
        const int d4 = k & 15;
        const float4 f = ((const float4*)(hs + ((size_t)(b * TT + t0 + t)) * (HH * DD) + h * DD))[d4];
        v4[t * 16 + (d4 ^ (t >> 3))] = f;
    }
    // ---- stage rot: [4 n][32 r][64 d] f32, slot = d4 ^ (r>>2) ----
    {
        const float* rh = rot + (size_t)h * (DD * NHASH * NHALF);
        float* rf = (float*)r4;
        #pragma unroll
        for (int p = 0; p < 32; ++p) {
            const int g  = tid + p * 256;   // global idx: d*128 + n*32 + r (coalesced)
            const int d  = g >> 7;
            const int nr = g & 127;
            const int nn = nr >> 5;
            const int r  = nr & 31;
            const int slot = (d >> 2) ^ (r >> 2);
            rf[((nn * 32 + r) * 16 + slot) * 4 + (d & 3)] = rh[g];
        }
    }
    __syncthreads();

    // ---- K loop: acc[i][j] (t = tg*8+i, r = rg*4+j), f64 ----
    double acc[8][4];
    #pragma unroll
    for (int i = 0; i < 8; ++i)
        #pragma unroll
        for (int j = 0; j < 4; ++j) acc[i][j] = 0.0;

    const int vbase = tg * 8 * 16;                 // float4 index of first own token row
    const int rbase = (n * 32 + rg * 4) * 16;      // float4 index of first own r row

    for (int s = 0; s < 16; ++s) {                 // d = s*4 .. s*4+3
        double rd[4][4];
        #pragma unroll
        for (int j = 0; j < 4; ++j) {
            const float4 rf = r4[rbase + j * 16 + (s ^ rg)];
            rd[j][0] = (double)rf.x; rd[j][1] = (double)rf.y;
            rd[j][2] = (double)rf.z; rd[j][3] = (double)rf.w;
        }
        #pragma unroll
        for (int i = 0; i < 8; ++i) {
            const float4 vf = v4[vbase + i * 16 + (s ^ tg)];
            const double v0 = (double)vf.x, v1 = (double)vf.y;
            const double v2 = (double)vf.z, v3 = (double)vf.w;
            #pragma unroll
            for (int j = 0; j < 4; ++j) {
                acc[i][j] += v0 * rd[j][0];
                acc[i][j] += v1 * rd[j][1];
                acc[i][j] += v2 * rd[j][2];
                acc[i][j] += v3 * rd[j][3];
            }
        }
    }

    // ---- epilogue: argmax/argmin over r per (n,t) ----
    __syncthreads();   // all LDS reads done; alias lds for partials
    float*    vmaxL = (float*)lds;            // [4][64][9]
    float*    vminL = (float*)(lds + 2304);
    uint32_t* imaxL = lds + 4608;
    uint32_t* iminL = lds + 6912;
    uint32_t* bkt   = lds + 9216;             // [4][64]

    #pragma unroll
    for (int i = 0; i < 8; ++i) {
        const int t = tg * 8 + i;
        float fmx = -INFINITY; int imx = 0;
        float fmn =  INFINITY; int imn = 0;
        #pragma unroll
        for (int j = 0; j < 4; ++j) {
            const float f = (float)acc[i][j];
            const int   r = rg * 4 + j;
            if (f > fmx) { fmx = f; imx = r; }
            if (f < fmn) { fmn = f; imn = r; }
        }
        const int o = (n * 64 + t) * 9 + rg;
        vmaxL[o] = fmx; vminL[o] = fmn;
        imaxL[o] = (uint32_t)imx; iminL[o] = (uint32_t)imn;
    }
    __syncthreads();
    {
        const int nn = tid >> 6;
        const int t  = tid & 63;
        float fmx = -INFINITY; int imx = 0;
        float fmn =  INFINITY; int imn = 0;
        #pragma unroll
        for (int g = 0; g < 8; ++g) {     // rg ascending -> r ascending: first-index tie-break
            const int o = (nn * 64 + t) * 9 + g;
            const float fx = vmaxL[o];
            const float fn = vminL[o];
            if (fx > fmx) { fmx = fx; imx = (int)imaxL[o]; }
            if (fn < fmn) { fmn = fn; imn = (int)iminL[o]; }
        }
        const uint32_t bucket = (fmx >= -fmn) ? (uint32_t)imx : (uint32_t)(NHALF + imn);
        bkt[nn * 64 + t] = bucket;
    }
    __syncthreads();
    if (tid < 64) {
        words[(size_t)bh * TT + t0 + tid] = bkt[tid]
                                          | (bkt[64  + tid] << 8)
                                          | (bkt[128 + tid] << 16)
                                          | (bkt[192 + tid] << 24);
    }
}

// ---------------- Phase 2: materialize the [B,H,T,T] mask (int32 0/1) ----------------
// 512-thread blocks, ROWS=32: one uint4 column-slice per thread (single
// prologue load), 32 fully-unrolled coalesced stores per thread.
#define ROWS 32
__device__ __forceinline__ uint32_t eq_any_byte(uint32_t a, uint32_t b) {
    const uint32_t x = a ^ b;
    return ((x - 0x01010101u) & ~x & 0x80808080u) ? 1u : 0u;
}

__global__ __launch_bounds__(512) void lsh_mask_kernel(
    const uint32_t* __restrict__ words,  // [BB*HH*TT]
    uint4* __restrict__ out)             // [BB*HH*TT][TT/4]
{
    const int bh  = blockIdx.x >> 6;            // TT/ROWS = 64 blocks per bh
    const int i0  = (blockIdx.x & 63) * ROWS;
    const int tid = threadIdx.x;                // 0..511, one uint4 of wj
    const uint32_t* wrow = words + (bh << 11);

    const uint4 wj = ((const uint4*)wrow)[tid];

    uint4* op = out + (((size_t)((bh << 11) + i0)) << 9) + tid;
    #pragma unroll
    for (int k = 0; k < ROWS; ++k) {
        const uint32_t wi = wrow[i0 + k];
        uint4 r;
        r.x = eq_any_byte(wi, wj.x); r.y = eq_any_byte(wi, wj.y);
        r.z = eq_any_byte(wi, wj.z); r.w = eq_any_byte(wi, wj.w);
        op[(size_t)k << 9] = r;
    }
}

extern "C" void kernel_launch(void* const* d_in, const int* in_sizes, int n_in,
                              void* d_out, int out_size, void* d_ws, size_t ws_size,
                              hipStream_t stream) {
    const float* hs  = (const float*)d_in[0];   // [2, 2048, 1024] f32
    const float* rot = (const float*)d_in[1];   // [16, 64, 4, 32] f32
    uint32_t* words  = (uint32_t*)d_ws;         // needs BB*HH*TT*4 = 256 KiB

    lsh_buckets_kernel<<<BB * HH * (TT / 64), 256, 0, stream>>>(hs, rot, words);
    lsh_mask_kernel<<<BB * HH * (TT / ROWS), 512, 0, stream>>>(words, (uint4*)d_out);
}